// Round 3
// baseline (1078.023 us; speedup 1.0000x reference)
//
#include <hip/hip_runtime.h>

// GCN encoder, fused gather formulation + bucketed CSR build.
// Pipeline (10 dispatches):
//   zero bcur | bucket_fill (packed append) | bscan | build_csr (per-bucket count/scan/fill)
//   out_init | K0: h0=x@Win+b -> {out+=h0@Ws0, hwA=(h0@Wg0)*dinv}
//   GT1: gather(hwA)->h1 -> {out+=h1@Ws1, hwB=(h1@Wg1)*dinv}
//   GT2: gather(hwB)->h2 -> {out+=h2@Ws2, hwA=(h2@Wg2)*dinv}
//   GT3: gather(hwA)->h3 -> hwB32=(h3@Wl)*dinv
//   GO : gather32(hwB32) -> out += dinv*acc
// Identity: gcn(h)[v] = dinv[v] * sum_{s in nbr(v) u {v}} (hW*dinv)[s] + b

#define HID 64
#define LAT 32
#define BSH 7          // 128 nodes per bucket
#define BCAP 4096      // bucket capacity (mean load ~2046, 45-sigma margin)

static inline int cdiv(long long a, long long b) { return (int)((a + b - 1) / b); }

// ---------------- CSR build ----------------

__global__ void zero_kernel(int* __restrict__ p, int n) {
    int i = blockIdx.x * blockDim.x + threadIdx.x;
    if (i < n) p[i] = 0;
}

// append packed (dst_local<<17 | src) into bucket region; sequential appends
// per bucket -> full cache lines instead of 4B scatter.
__global__ void bucket_fill_kernel(const int* __restrict__ src, const int* __restrict__ dst,
                                   int* __restrict__ bcur, unsigned* __restrict__ bbuf, int E) {
    int e = blockIdx.x * blockDim.x + threadIdx.x;
    if (e >= E) return;
    int s = src[e], d = dst[e];
    int b = d >> BSH;
    int pos = atomicAdd(&bcur[b], 1);
    if (pos < BCAP)  // statistically impossible to overflow; guard vs corruption
        bbuf[(size_t)b * BCAP + pos] = ((unsigned)(d & ((1 << BSH) - 1)) << 17) | (unsigned)s;
}

// exclusive scan over bucket counts (single block, NB <= 1024)
__global__ void bscan_kernel(const int* __restrict__ bcur, int* __restrict__ bstart, int nb) {
    __shared__ int s[1024];
    int t = threadIdx.x;
    int v = (t < nb) ? bcur[t] : 0;
    s[t] = v;
    __syncthreads();
    for (int off = 1; off < 1024; off <<= 1) {
        int x = (t >= off) ? s[t - off] : 0;
        __syncthreads();
        s[t] += x;
        __syncthreads();
    }
    if (t < nb) bstart[t] = s[t] - v;
}

// one block per bucket: LDS per-node count -> scan -> clustered csr fill.
// also emits rowstart[v] and dinv[v] = rsqrt(in_deg+1).
__global__ void build_csr_kernel(const int* __restrict__ bcur, const int* __restrict__ bstart,
                                 const unsigned* __restrict__ bbuf, int* __restrict__ csr,
                                 int* __restrict__ rowstart, float* __restrict__ dinv,
                                 int n, int E) {
    __shared__ int lcount[128], lpre[128], lcur[128];
    int b = blockIdx.x, t = threadIdx.x;
    int cnt = bcur[b];
    if (cnt > BCAP) cnt = BCAP;
    int bst = bstart[b];
    size_t ebase = (size_t)b * BCAP;

    if (t < 128) lcount[t] = 0;
    __syncthreads();
    for (int i = t; i < cnt; i += 256)
        atomicAdd(&lcount[bbuf[ebase + i] >> 17], 1);
    __syncthreads();
    if (t < 128) lpre[t] = lcount[t];
    __syncthreads();
    for (int off = 1; off < 128; off <<= 1) {
        int x = (t < 128 && t >= off) ? lpre[t - off] : 0;
        __syncthreads();
        if (t < 128) lpre[t] += x;
        __syncthreads();
    }
    if (t < 128) {
        int excl = lpre[t] - lcount[t];
        lcur[t] = excl;
        int v = (b << BSH) + t;
        if (v < n) {
            rowstart[v] = bst + excl;
            dinv[v] = rsqrtf((float)(lcount[t] + 1));
        }
    }
    if (b == 0 && t == 0) rowstart[n] = E;
    __syncthreads();
    for (int i = t; i < cnt; i += 256) {
        unsigned p = bbuf[ebase + i];
        int pos = bst + atomicAdd(&lcur[p >> 17], 1);
        csr[pos] = (int)(p & 0x1FFFFu);
    }
}

// ---------------- output init: d_out[v,c] = bl[c] + sum_i bs[i,c] ----------------

__global__ void out_init_kernel(const float* __restrict__ bl, const float* __restrict__ bs,
                                float* __restrict__ out, int n) {
    long long t = (long long)blockIdx.x * blockDim.x + threadIdx.x;
    if (t >= (long long)n * LAT) return;
    int c = (int)(t & (LAT - 1));
    out[t] = bl[c] + bs[c] + bs[LAT + c] + bs[2 * LAT + c];
}

// ---------------- K0: input layer, fused ----------------
// 16 rows/block, 256 thr = 16 rows x 16 lanes, 4 cols per lane (float4).
// h0 = x@Win + bin (LDS); hw = (h0@Wg0)*dinv; out += h0@Ws0.

__global__ void input_fused_kernel(const float* __restrict__ x, const float* __restrict__ Win,
                                   const float* __restrict__ bin, const float* __restrict__ Wg0,
                                   const float* __restrict__ Ws0, const float* __restrict__ dinv,
                                   float* __restrict__ hw, float* __restrict__ out, int n) {
    __shared__ float xr[16 * 132];  // +4 pad: 4 row-addrs per wave land on distinct banks
    __shared__ float h0[16 * 68];   // +4 pad, 272B row stride (16B aligned)
    int t = threadIdx.x;
    long long rbase = (long long)blockIdx.x * 16;

    for (int i = t; i < 16 * 128; i += 256) {
        int rr = i >> 7, kk = i & 127;
        xr[rr * 132 + kk] = (rbase + rr < n) ? x[(rbase + rr) * 128 + kk] : 0.f;
    }
    __syncthreads();

    int lr = t >> 4;   // row 0..15
    int lc = t & 15;   // col group: cols 4lc..4lc+3
    int r = (int)rbase + lr;

    float4 acc = *(const float4*)&bin[4 * lc];
#pragma unroll 16
    for (int k = 0; k < 128; ++k) {
        float xv = xr[lr * 132 + k];
        float4 w = *(const float4*)&Win[k * 64 + 4 * lc];
        acc.x = fmaf(xv, w.x, acc.x);
        acc.y = fmaf(xv, w.y, acc.y);
        acc.z = fmaf(xv, w.z, acc.z);
        acc.w = fmaf(xv, w.w, acc.w);
    }
    *(float4*)&h0[lr * 68 + 4 * lc] = acc;
    __syncthreads();

    if (r < n) {
        float di = dinv[r];
        float4 a = make_float4(0.f, 0.f, 0.f, 0.f);
#pragma unroll 16
        for (int k = 0; k < 64; ++k) {
            float hv = h0[lr * 68 + k];
            float4 w = *(const float4*)&Wg0[k * 64 + 4 * lc];
            a.x = fmaf(hv, w.x, a.x);
            a.y = fmaf(hv, w.y, a.y);
            a.z = fmaf(hv, w.z, a.z);
            a.w = fmaf(hv, w.w, a.w);
        }
        a.x *= di; a.y *= di; a.z *= di; a.w *= di;
        *(float4*)&hw[(size_t)r * 64 + 4 * lc] = a;

        if (lc < 8) {  // 32 skip cols
            float4 s = make_float4(0.f, 0.f, 0.f, 0.f);
#pragma unroll 16
            for (int k = 0; k < 64; ++k) {
                float hv = h0[lr * 68 + k];
                float4 w = *(const float4*)&Ws0[k * 32 + 4 * lc];
                s.x = fmaf(hv, w.x, s.x);
                s.y = fmaf(hv, w.y, s.y);
                s.z = fmaf(hv, w.z, s.z);
                s.w = fmaf(hv, w.w, s.w);
            }
            float4* op = (float4*)(out + (size_t)r * 32 + 4 * lc);
            float4 o = *op;
            o.x += s.x; o.y += s.y; o.z += s.z; o.w += s.w;
            *op = o;
        }
    }
}

// ---------------- fused gather + transform ----------------
// 16 nodes/block, 16 lanes per node (float4 over 64 ch). One wave gathers 4
// edges per load instr. Then h = lrelu(dinv*acc + bias), and (through LDS):
//   !LAST: hwout = (h@Wg)*dinv [64c], out += h@Ws [32c]
//    LAST: hwout32 = (h@Ws)*dinv  (Ws carries Wl)

template <bool LAST>
__global__ void gather_transform_kernel(const int* __restrict__ rowstart, const int* __restrict__ csr,
                                        const float* __restrict__ dinv, const float* __restrict__ hwin,
                                        const float* __restrict__ bias, const float* __restrict__ Wg,
                                        const float* __restrict__ Ws, float* __restrict__ hwout,
                                        float* __restrict__ out, int n) {
    __shared__ float hL[16 * 68];
    int t = threadIdx.x;
    int lr = t >> 4, lc = t & 15;
    int v = blockIdx.x * 16 + lr;
    bool valid = v < n;

    int beg = 0, end = 0;
    float di = 0.f;
    float4 acc = make_float4(0.f, 0.f, 0.f, 0.f);
    if (valid) {
        beg = rowstart[v];
        end = rowstart[v + 1];
        di = dinv[v];
        acc = *(const float4*)&hwin[(size_t)v * 64 + 4 * lc];  // self (pre-scaled)
    }
    const float* base = hwin + 4 * lc;
    int e = beg;
    for (; e + 3 < end; e += 4) {  // 4 independent load chains
        int s0 = csr[e], s1 = csr[e + 1], s2 = csr[e + 2], s3 = csr[e + 3];
        float4 a0 = *(const float4*)&base[(size_t)s0 * 64];
        float4 a1 = *(const float4*)&base[(size_t)s1 * 64];
        float4 a2 = *(const float4*)&base[(size_t)s2 * 64];
        float4 a3 = *(const float4*)&base[(size_t)s3 * 64];
        acc.x += (a0.x + a1.x) + (a2.x + a3.x);
        acc.y += (a0.y + a1.y) + (a2.y + a3.y);
        acc.z += (a0.z + a1.z) + (a2.z + a3.z);
        acc.w += (a0.w + a1.w) + (a2.w + a3.w);
    }
    for (; e < end; ++e) {
        float4 a0 = *(const float4*)&base[(size_t)csr[e] * 64];
        acc.x += a0.x; acc.y += a0.y; acc.z += a0.z; acc.w += a0.w;
    }
    float4 b4 = *(const float4*)&bias[4 * lc];
    float4 h;
    h.x = di * acc.x + b4.x; h.x = h.x > 0.f ? h.x : 0.2f * h.x;
    h.y = di * acc.y + b4.y; h.y = h.y > 0.f ? h.y : 0.2f * h.y;
    h.z = di * acc.z + b4.z; h.z = h.z > 0.f ? h.z : 0.2f * h.z;
    h.w = di * acc.w + b4.w; h.w = h.w > 0.f ? h.w : 0.2f * h.w;
    *(float4*)&hL[lr * 68 + 4 * lc] = h;
    __syncthreads();

    if (!LAST) {
        if (valid) {
            float4 a = make_float4(0.f, 0.f, 0.f, 0.f);
#pragma unroll 16
            for (int k = 0; k < 64; ++k) {
                float hv = hL[lr * 68 + k];
                float4 w = *(const float4*)&Wg[k * 64 + 4 * lc];
                a.x = fmaf(hv, w.x, a.x);
                a.y = fmaf(hv, w.y, a.y);
                a.z = fmaf(hv, w.z, a.z);
                a.w = fmaf(hv, w.w, a.w);
            }
            a.x *= di; a.y *= di; a.z *= di; a.w *= di;
            *(float4*)&hwout[(size_t)v * 64 + 4 * lc] = a;

            if (lc < 8) {
                float4 s = make_float4(0.f, 0.f, 0.f, 0.f);
#pragma unroll 16
                for (int k = 0; k < 64; ++k) {
                    float hv = hL[lr * 68 + k];
                    float4 w = *(const float4*)&Ws[k * 32 + 4 * lc];
                    s.x = fmaf(hv, w.x, s.x);
                    s.y = fmaf(hv, w.y, s.y);
                    s.z = fmaf(hv, w.z, s.z);
                    s.w = fmaf(hv, w.w, s.w);
                }
                float4* op = (float4*)(out + (size_t)v * 32 + 4 * lc);
                float4 o = *op;
                o.x += s.x; o.y += s.y; o.z += s.z; o.w += s.w;
                *op = o;
            }
        }
    } else {
        if (valid && lc < 8) {
            float4 a = make_float4(0.f, 0.f, 0.f, 0.f);
#pragma unroll 16
            for (int k = 0; k < 64; ++k) {
                float hv = hL[lr * 68 + k];
                float4 w = *(const float4*)&Ws[k * 32 + 4 * lc];  // Ws == Wl
                a.x = fmaf(hv, w.x, a.x);
                a.y = fmaf(hv, w.y, a.y);
                a.z = fmaf(hv, w.z, a.z);
                a.w = fmaf(hv, w.w, a.w);
            }
            a.x *= di; a.y *= di; a.z *= di; a.w *= di;
            *(float4*)&hwout[(size_t)v * 32 + 4 * lc] = a;
        }
    }
}

// ---------------- final gather into output (32 ch, 8 lanes/node) ----------------

__global__ void gather_out_kernel(const int* __restrict__ rowstart, const int* __restrict__ csr,
                                  const float* __restrict__ dinv, const float* __restrict__ hwl,
                                  float* __restrict__ out, int n) {
    int t = threadIdx.x;
    int lr = t >> 3, lc = t & 7;
    int v = blockIdx.x * 32 + lr;
    if (v >= n) return;
    int beg = rowstart[v], end = rowstart[v + 1];
    float4 acc = *(const float4*)&hwl[(size_t)v * 32 + 4 * lc];
    const float* base = hwl + 4 * lc;
    int e = beg;
    for (; e + 3 < end; e += 4) {
        int s0 = csr[e], s1 = csr[e + 1], s2 = csr[e + 2], s3 = csr[e + 3];
        float4 a0 = *(const float4*)&base[(size_t)s0 * 32];
        float4 a1 = *(const float4*)&base[(size_t)s1 * 32];
        float4 a2 = *(const float4*)&base[(size_t)s2 * 32];
        float4 a3 = *(const float4*)&base[(size_t)s3 * 32];
        acc.x += (a0.x + a1.x) + (a2.x + a3.x);
        acc.y += (a0.y + a1.y) + (a2.y + a3.y);
        acc.z += (a0.z + a1.z) + (a2.z + a3.z);
        acc.w += (a0.w + a1.w) + (a2.w + a3.w);
    }
    for (; e < end; ++e) {
        float4 a0 = *(const float4*)&base[(size_t)csr[e] * 32];
        acc.x += a0.x; acc.y += a0.y; acc.z += a0.z; acc.w += a0.w;
    }
    float di = dinv[v];
    float4* op = (float4*)(out + (size_t)v * 32 + 4 * lc);
    float4 o = *op;
    o.x += di * acc.x; o.y += di * acc.y; o.z += di * acc.z; o.w += di * acc.w;
    *op = o;
}

// ---------------- launch ----------------

extern "C" void kernel_launch(void* const* d_in, const int* in_sizes, int n_in,
                              void* d_out, int out_size, void* d_ws, size_t ws_size,
                              hipStream_t stream) {
    const float* x    = (const float*)d_in[0];
    const int*   ei   = (const int*)d_in[1];
    const float* W_in = (const float*)d_in[2];
    const float* b_in = (const float*)d_in[3];
    const float* Wg   = (const float*)d_in[4];  // [3][64][64]
    const float* bg   = (const float*)d_in[5];  // [3][64]
    const float* Ws   = (const float*)d_in[6];  // [3][64][32]
    const float* bs   = (const float*)d_in[7];  // [3][32]
    const float* Wl   = (const float*)d_in[8];  // [64][32]
    const float* bl   = (const float*)d_in[9];  // [32]

    const int N = in_sizes[0] / 128;
    const int E = in_sizes[1] / 2;
    const int NB = cdiv(N, 1 << BSH);
    const int* srcp = ei;
    const int* dstp = ei + E;

    // workspace (16B-aligned arrays first)
    char* p = (char*)d_ws;
    float*    hwA      = (float*)p;    p += (size_t)N * HID * 4;
    float*    hwB      = (float*)p;    p += (size_t)N * HID * 4;
    unsigned* bbuf     = (unsigned*)p; p += (size_t)NB * BCAP * 4;
    int*      csr      = (int*)p;      p += (size_t)E * 4;
    int*      rowstart = (int*)p;      p += ((size_t)N + 1) * 4;
    float*    dinv     = (float*)p;    p += (size_t)N * 4;
    int*      bcur     = (int*)p;      p += (size_t)NB * 4;
    int*      bstart   = (int*)p;      p += (size_t)NB * 4;
    float*    out      = (float*)d_out;

    const int B = 256;

    // CSR build
    zero_kernel<<<cdiv(NB, B), B, 0, stream>>>(bcur, NB);
    bucket_fill_kernel<<<cdiv(E, B), B, 0, stream>>>(srcp, dstp, bcur, bbuf, E);
    bscan_kernel<<<1, 1024, 0, stream>>>(bcur, bstart, NB);
    build_csr_kernel<<<NB, B, 0, stream>>>(bcur, bstart, bbuf, csr, rowstart, dinv, N, E);

    out_init_kernel<<<cdiv((long long)N * LAT, B), B, 0, stream>>>(bl, bs, out, N);

    // K0: h0 -> {out += h0@Ws[0], hwA = (h0@Wg[0])*dinv}
    input_fused_kernel<<<cdiv(N, 16), B, 0, stream>>>(
        x, W_in, b_in, Wg, Ws, dinv, hwA, out, N);

    // GT1: gather(hwA) -> h1 -> {out += h1@Ws[1], hwB = (h1@Wg[1])*dinv}
    gather_transform_kernel<false><<<cdiv(N, 16), B, 0, stream>>>(
        rowstart, csr, dinv, hwA, bg, Wg + 4096, Ws + 2048, hwB, out, N);

    // GT2: gather(hwB) -> h2 -> {out += h2@Ws[2], hwA = (h2@Wg[2])*dinv}
    gather_transform_kernel<false><<<cdiv(N, 16), B, 0, stream>>>(
        rowstart, csr, dinv, hwB, bg + 64, Wg + 8192, Ws + 4096, hwA, out, N);

    // GT3 (last): gather(hwA) -> h3 -> hwB[:, :32] = (h3@Wl)*dinv
    gather_transform_kernel<true><<<cdiv(N, 16), B, 0, stream>>>(
        rowstart, csr, dinv, hwA, bg + 128, nullptr, Wl, hwB, nullptr, N);

    // GO: out += dinv * gather32(hwB)
    gather_out_kernel<<<cdiv(N, 32), B, 0, stream>>>(rowstart, csr, dinv, hwB, out, N);
}

// Round 5
// 814.948 us; speedup vs baseline: 1.3228x; 1.3228x over previous
//
#include <hip/hip_runtime.h>

// GCN encoder, fused gather formulation + fine-bucket CSR build.
// CSR build contention model: same-address atomics serialize at ~184ns/op
// (measured r3: 782 buckets -> 2046/addr -> 377us). BSH=3 gives 12500
// buckets, 128/addr -> ~24us serial floor.
// Pipeline (10 dispatches):
//   zero bcur | bucket_fill | bscan | build_csr
//   out_init | K0: h0=x@Win+b -> {out+=h0@Ws0, hwA=(h0@Wg0)*dinv}
//   GT1: gather(hwA)->h1 -> {out+=h1@Ws1, hwB=(h1@Wg1)*dinv}
//   GT2: gather(hwB)->h2 -> {out+=h2@Ws2, hwA=(h2@Wg2)*dinv}
//   GT3: gather(hwA)->h3 -> hwB32=(h3@Wl)*dinv
//   GO : gather32(hwB32) -> out += dinv*acc
// Identity: gcn(h)[v] = dinv[v] * sum_{s in nbr(v) u {v}} (hW*dinv)[s] + b

#define HID 64
#define LAT 32
#define BSH 3          // 8 nodes per bucket
#define BCAP 256       // bucket capacity (mean 128, ~11 sigma margin)

static inline int cdiv(long long a, long long b) { return (int)((a + b - 1) / b); }

// ---------------- CSR build ----------------

__global__ void zero_kernel(int* __restrict__ p, int n) {
    int i = blockIdx.x * blockDim.x + threadIdx.x;
    if (i < n) p[i] = 0;
}

// append packed (dst_local<<17 | src) into bucket region
__global__ void bucket_fill_kernel(const int* __restrict__ src, const int* __restrict__ dst,
                                   int* __restrict__ bcur, unsigned* __restrict__ bbuf, int E) {
    int e = blockIdx.x * blockDim.x + threadIdx.x;
    if (e >= E) return;
    int s = src[e], d = dst[e];
    int b = d >> BSH;
    int pos = atomicAdd(&bcur[b], 1);
    if (pos < BCAP)  // statistically impossible to overflow; guard vs corruption
        bbuf[(size_t)b * BCAP + pos] = ((unsigned)(d & ((1 << BSH) - 1)) << 17) | (unsigned)s;
}

// exclusive scan over bucket counts; single block, chunked with carry
__global__ void bscan_kernel(const int* __restrict__ bcur, int* __restrict__ bstart, int nb) {
    __shared__ int s[1024];
    __shared__ int carry;
    int t = threadIdx.x;
    if (t == 0) carry = 0;
    __syncthreads();
    for (int base = 0; base < nb; base += 1024) {
        int i = base + t;
        int v = (i < nb) ? bcur[i] : 0;
        s[t] = v;
        __syncthreads();
        for (int off = 1; off < 1024; off <<= 1) {
            int x = (t >= off) ? s[t - off] : 0;
            __syncthreads();
            s[t] += x;
            __syncthreads();
        }
        if (i < nb) bstart[i] = carry + s[t] - v;
        __syncthreads();  // all reads of carry done
        if (t == 1023) carry += s[1023];
        __syncthreads();
    }
}

// one block (128 thr) per bucket: registers hold the <=256 records between
// count and fill passes; per-node LDS count -> serial scan(8) -> clustered fill.
// also emits rowstart[v] and dinv[v] = rsqrt(in_deg+1).
__global__ void build_csr_kernel(const int* __restrict__ bcur, const int* __restrict__ bstart,
                                 const unsigned* __restrict__ bbuf, int* __restrict__ csr,
                                 int* __restrict__ rowstart, float* __restrict__ dinv,
                                 int n, int E) {
    __shared__ int lcount[1 << BSH], lpre[1 << BSH], lcur[1 << BSH];
    int b = blockIdx.x, t = threadIdx.x;
    int cnt = bcur[b];
    if (cnt > BCAP) cnt = BCAP;
    int bst = bstart[b];
    size_t ebase = (size_t)b * BCAP;

    if (t < (1 << BSH)) lcount[t] = 0;
    __syncthreads();

    unsigned rec[2];
    int nrec = 0;
    for (int i = t; i < cnt; i += 128) {
        unsigned p = bbuf[ebase + i];
        rec[nrec++] = p;
        atomicAdd(&lcount[p >> 17], 1);
    }
    __syncthreads();

    if (t == 0) {
        int run = 0;
        for (int k = 0; k < (1 << BSH); ++k) {
            lpre[k] = run;
            lcur[k] = run;
            run += lcount[k];
        }
    }
    __syncthreads();

    if (t < (1 << BSH)) {
        int v = (b << BSH) + t;
        if (v < n) {
            rowstart[v] = bst + lpre[t];
            dinv[v] = rsqrtf((float)(lcount[t] + 1));
        }
    }
    if (b == 0 && t == 0) rowstart[n] = E;

    for (int j = 0; j < nrec; ++j) {
        unsigned p = rec[j];
        int pos = bst + atomicAdd(&lcur[p >> 17], 1);
        csr[pos] = (int)(p & 0x1FFFFu);
    }
}

// ---------------- output init: d_out[v,c] = bl[c] + sum_i bs[i,c] ----------------

__global__ void out_init_kernel(const float* __restrict__ bl, const float* __restrict__ bs,
                                float* __restrict__ out, int n) {
    long long t = (long long)blockIdx.x * blockDim.x + threadIdx.x;
    if (t >= (long long)n * LAT) return;
    int c = (int)(t & (LAT - 1));
    out[t] = bl[c] + bs[c] + bs[LAT + c] + bs[2 * LAT + c];
}

// ---------------- K0: input layer, fused ----------------
// 16 rows/block, 256 thr = 16 rows x 16 lanes, 4 cols per lane (float4).
// h0 = x@Win + bin (LDS); hw = (h0@Wg0)*dinv; out += h0@Ws0.

__global__ void input_fused_kernel(const float* __restrict__ x, const float* __restrict__ Win,
                                   const float* __restrict__ bin, const float* __restrict__ Wg0,
                                   const float* __restrict__ Ws0, const float* __restrict__ dinv,
                                   float* __restrict__ hw, float* __restrict__ out, int n) {
    __shared__ float xr[16 * 132];
    __shared__ float h0[16 * 68];
    int t = threadIdx.x;
    long long rbase = (long long)blockIdx.x * 16;

    for (int i = t; i < 16 * 128; i += 256) {
        int rr = i >> 7, kk = i & 127;
        xr[rr * 132 + kk] = (rbase + rr < n) ? x[(rbase + rr) * 128 + kk] : 0.f;
    }
    __syncthreads();

    int lr = t >> 4;
    int lc = t & 15;
    int r = (int)rbase + lr;

    float4 acc = *(const float4*)&bin[4 * lc];
#pragma unroll 16
    for (int k = 0; k < 128; ++k) {
        float xv = xr[lr * 132 + k];
        float4 w = *(const float4*)&Win[k * 64 + 4 * lc];
        acc.x = fmaf(xv, w.x, acc.x);
        acc.y = fmaf(xv, w.y, acc.y);
        acc.z = fmaf(xv, w.z, acc.z);
        acc.w = fmaf(xv, w.w, acc.w);
    }
    *(float4*)&h0[lr * 68 + 4 * lc] = acc;
    __syncthreads();

    if (r < n) {
        float di = dinv[r];
        float4 a = make_float4(0.f, 0.f, 0.f, 0.f);
#pragma unroll 16
        for (int k = 0; k < 64; ++k) {
            float hv = h0[lr * 68 + k];
            float4 w = *(const float4*)&Wg0[k * 64 + 4 * lc];
            a.x = fmaf(hv, w.x, a.x);
            a.y = fmaf(hv, w.y, a.y);
            a.z = fmaf(hv, w.z, a.z);
            a.w = fmaf(hv, w.w, a.w);
        }
        a.x *= di; a.y *= di; a.z *= di; a.w *= di;
        *(float4*)&hw[(size_t)r * 64 + 4 * lc] = a;

        if (lc < 8) {
            float4 s = make_float4(0.f, 0.f, 0.f, 0.f);
#pragma unroll 16
            for (int k = 0; k < 64; ++k) {
                float hv = h0[lr * 68 + k];
                float4 w = *(const float4*)&Ws0[k * 32 + 4 * lc];
                s.x = fmaf(hv, w.x, s.x);
                s.y = fmaf(hv, w.y, s.y);
                s.z = fmaf(hv, w.z, s.z);
                s.w = fmaf(hv, w.w, s.w);
            }
            float4* op = (float4*)(out + (size_t)r * 32 + 4 * lc);
            float4 o = *op;
            o.x += s.x; o.y += s.y; o.z += s.z; o.w += s.w;
            *op = o;
        }
    }
}

// ---------------- fused gather + transform ----------------

template <bool LAST>
__global__ void gather_transform_kernel(const int* __restrict__ rowstart, const int* __restrict__ csr,
                                        const float* __restrict__ dinv, const float* __restrict__ hwin,
                                        const float* __restrict__ bias, const float* __restrict__ Wg,
                                        const float* __restrict__ Ws, float* __restrict__ hwout,
                                        float* __restrict__ out, int n) {
    __shared__ float hL[16 * 68];
    int t = threadIdx.x;
    int lr = t >> 4, lc = t & 15;
    int v = blockIdx.x * 16 + lr;
    bool valid = v < n;

    int beg = 0, end = 0;
    float di = 0.f;
    float4 acc = make_float4(0.f, 0.f, 0.f, 0.f);
    if (valid) {
        beg = rowstart[v];
        end = rowstart[v + 1];
        di = dinv[v];
        acc = *(const float4*)&hwin[(size_t)v * 64 + 4 * lc];  // self (pre-scaled)
    }
    const float* base = hwin + 4 * lc;
    int e = beg;
    for (; e + 3 < end; e += 4) {
        int s0 = csr[e], s1 = csr[e + 1], s2 = csr[e + 2], s3 = csr[e + 3];
        float4 a0 = *(const float4*)&base[(size_t)s0 * 64];
        float4 a1 = *(const float4*)&base[(size_t)s1 * 64];
        float4 a2 = *(const float4*)&base[(size_t)s2 * 64];
        float4 a3 = *(const float4*)&base[(size_t)s3 * 64];
        acc.x += (a0.x + a1.x) + (a2.x + a3.x);
        acc.y += (a0.y + a1.y) + (a2.y + a3.y);
        acc.z += (a0.z + a1.z) + (a2.z + a3.z);
        acc.w += (a0.w + a1.w) + (a2.w + a3.w);
    }
    for (; e < end; ++e) {
        float4 a0 = *(const float4*)&base[(size_t)csr[e] * 64];
        acc.x += a0.x; acc.y += a0.y; acc.z += a0.z; acc.w += a0.w;
    }
    float4 b4 = *(const float4*)&bias[4 * lc];
    float4 h;
    h.x = di * acc.x + b4.x; h.x = h.x > 0.f ? h.x : 0.2f * h.x;
    h.y = di * acc.y + b4.y; h.y = h.y > 0.f ? h.y : 0.2f * h.y;
    h.z = di * acc.z + b4.z; h.z = h.z > 0.f ? h.z : 0.2f * h.z;
    h.w = di * acc.w + b4.w; h.w = h.w > 0.f ? h.w : 0.2f * h.w;
    *(float4*)&hL[lr * 68 + 4 * lc] = h;
    __syncthreads();

    if (!LAST) {
        if (valid) {
            float4 a = make_float4(0.f, 0.f, 0.f, 0.f);
#pragma unroll 16
            for (int k = 0; k < 64; ++k) {
                float hv = hL[lr * 68 + k];
                float4 w = *(const float4*)&Wg[k * 64 + 4 * lc];
                a.x = fmaf(hv, w.x, a.x);
                a.y = fmaf(hv, w.y, a.y);
                a.z = fmaf(hv, w.z, a.z);
                a.w = fmaf(hv, w.w, a.w);
            }
            a.x *= di; a.y *= di; a.z *= di; a.w *= di;
            *(float4*)&hwout[(size_t)v * 64 + 4 * lc] = a;

            if (lc < 8) {
                float4 s = make_float4(0.f, 0.f, 0.f, 0.f);
#pragma unroll 16
                for (int k = 0; k < 64; ++k) {
                    float hv = hL[lr * 68 + k];
                    float4 w = *(const float4*)&Ws[k * 32 + 4 * lc];
                    s.x = fmaf(hv, w.x, s.x);
                    s.y = fmaf(hv, w.y, s.y);
                    s.z = fmaf(hv, w.z, s.z);
                    s.w = fmaf(hv, w.w, s.w);
                }
                float4* op = (float4*)(out + (size_t)v * 32 + 4 * lc);
                float4 o = *op;
                o.x += s.x; o.y += s.y; o.z += s.z; o.w += s.w;
                *op = o;
            }
        }
    } else {
        if (valid && lc < 8) {
            float4 a = make_float4(0.f, 0.f, 0.f, 0.f);
#pragma unroll 16
            for (int k = 0; k < 64; ++k) {
                float hv = hL[lr * 68 + k];
                float4 w = *(const float4*)&Ws[k * 32 + 4 * lc];  // Ws == Wl
                a.x = fmaf(hv, w.x, a.x);
                a.y = fmaf(hv, w.y, a.y);
                a.z = fmaf(hv, w.z, a.z);
                a.w = fmaf(hv, w.w, a.w);
            }
            a.x *= di; a.y *= di; a.z *= di; a.w *= di;
            *(float4*)&hwout[(size_t)v * 32 + 4 * lc] = a;
        }
    }
}

// ---------------- final gather into output (32 ch, 8 lanes/node) ----------------

__global__ void gather_out_kernel(const int* __restrict__ rowstart, const int* __restrict__ csr,
                                  const float* __restrict__ dinv, const float* __restrict__ hwl,
                                  float* __restrict__ out, int n) {
    int t = threadIdx.x;
    int lr = t >> 3, lc = t & 7;
    int v = blockIdx.x * 32 + lr;
    if (v >= n) return;
    int beg = rowstart[v], end = rowstart[v + 1];
    float4 acc = *(const float4*)&hwl[(size_t)v * 32 + 4 * lc];
    const float* base = hwl + 4 * lc;
    int e = beg;
    for (; e + 3 < end; e += 4) {
        int s0 = csr[e], s1 = csr[e + 1], s2 = csr[e + 2], s3 = csr[e + 3];
        float4 a0 = *(const float4*)&base[(size_t)s0 * 32];
        float4 a1 = *(const float4*)&base[(size_t)s1 * 32];
        float4 a2 = *(const float4*)&base[(size_t)s2 * 32];
        float4 a3 = *(const float4*)&base[(size_t)s3 * 32];
        acc.x += (a0.x + a1.x) + (a2.x + a3.x);
        acc.y += (a0.y + a1.y) + (a2.y + a3.y);
        acc.z += (a0.z + a1.z) + (a2.z + a3.z);
        acc.w += (a0.w + a1.w) + (a2.w + a3.w);
    }
    for (; e < end; ++e) {
        float4 a0 = *(const float4*)&base[(size_t)csr[e] * 32];
        acc.x += a0.x; acc.y += a0.y; acc.z += a0.z; acc.w += a0.w;
    }
    float di = dinv[v];
    float4* op = (float4*)(out + (size_t)v * 32 + 4 * lc);
    float4 o = *op;
    o.x += di * acc.x; o.y += di * acc.y; o.z += di * acc.z; o.w += di * acc.w;
    *op = o;
}

// ---------------- launch ----------------

extern "C" void kernel_launch(void* const* d_in, const int* in_sizes, int n_in,
                              void* d_out, int out_size, void* d_ws, size_t ws_size,
                              hipStream_t stream) {
    const float* x    = (const float*)d_in[0];
    const int*   ei   = (const int*)d_in[1];
    const float* W_in = (const float*)d_in[2];
    const float* b_in = (const float*)d_in[3];
    const float* Wg   = (const float*)d_in[4];  // [3][64][64]
    const float* bg   = (const float*)d_in[5];  // [3][64]
    const float* Ws   = (const float*)d_in[6];  // [3][64][32]
    const float* bs   = (const float*)d_in[7];  // [3][32]
    const float* Wl   = (const float*)d_in[8];  // [64][32]
    const float* bl   = (const float*)d_in[9];  // [32]

    const int N = in_sizes[0] / 128;
    const int E = in_sizes[1] / 2;
    const int NB = cdiv(N, 1 << BSH);
    const int* srcp = ei;
    const int* dstp = ei + E;

    // workspace (16B-aligned arrays first)
    char* p = (char*)d_ws;
    float*    hwA      = (float*)p;    p += (size_t)N * HID * 4;
    float*    hwB      = (float*)p;    p += (size_t)N * HID * 4;
    unsigned* bbuf     = (unsigned*)p; p += (size_t)NB * BCAP * 4;
    int*      csr      = (int*)p;      p += (size_t)E * 4;
    int*      rowstart = (int*)p;      p += ((size_t)N + 1) * 4;
    float*    dinv     = (float*)p;    p += (size_t)N * 4;
    int*      bcur     = (int*)p;      p += (size_t)NB * 4;
    int*      bstart   = (int*)p;      p += (size_t)NB * 4;
    float*    out      = (float*)d_out;

    const int B = 256;

    // CSR build
    zero_kernel<<<cdiv(NB, B), B, 0, stream>>>(bcur, NB);
    bucket_fill_kernel<<<cdiv(E, B), B, 0, stream>>>(srcp, dstp, bcur, bbuf, E);
    bscan_kernel<<<1, 1024, 0, stream>>>(bcur, bstart, NB);
    build_csr_kernel<<<NB, 128, 0, stream>>>(bcur, bstart, bbuf, csr, rowstart, dinv, N, E);

    out_init_kernel<<<cdiv((long long)N * LAT, B), B, 0, stream>>>(bl, bs, out, N);

    // K0
    input_fused_kernel<<<cdiv(N, 16), B, 0, stream>>>(
        x, W_in, b_in, Wg, Ws, dinv, hwA, out, N);

    // GT1
    gather_transform_kernel<false><<<cdiv(N, 16), B, 0, stream>>>(
        rowstart, csr, dinv, hwA, bg, Wg + 4096, Ws + 2048, hwB, out, N);

    // GT2
    gather_transform_kernel<false><<<cdiv(N, 16), B, 0, stream>>>(
        rowstart, csr, dinv, hwB, bg + 64, Wg + 8192, Ws + 4096, hwA, out, N);

    // GT3 (last)
    gather_transform_kernel<true><<<cdiv(N, 16), B, 0, stream>>>(
        rowstart, csr, dinv, hwA, bg + 128, nullptr, Wl, hwB, nullptr, N);

    // GO
    gather_out_kernel<<<cdiv(N, 32), B, 0, stream>>>(rowstart, csr, dinv, hwB, out, N);
}

// Round 6
// 601.490 us; speedup vs baseline: 1.7923x; 1.3549x over previous
//
#include <hip/hip_runtime.h>

// GCN encoder, fused gather formulation + fine-bucket CSR build.
// Measured models so far (MI355X):
//  - same-address atomic chain ~184ns/op (r3) -> fine buckets (BSH=3, 128/addr).
//  - 1-output/thread dense transform = latency-stalled (r5: VALUBusy 14%,
//    HBM 4%, 210us) -> 4x4 register tiling: 16 FMA per {1 global float4 + 4
//    LDS reads}, 16 independent accumulators for ILP.
// Pipeline (10 dispatches):
//   zero | bucket_fill | bscan | build_csr | out_init
//   K0 : h0=x@Win+b -> {out+=h0@Ws0, hwA=(h0@Wg0)*dinv}
//   GT1: gather(hwA)->h1 -> {out+=h1@Ws1, hwB=(h1@Wg1)*dinv}
//   GT2: gather(hwB)->h2 -> {out+=h2@Ws2, hwA=(h2@Wg2)*dinv}
//   GT3: gather(hwA)->h3 -> hwB32=(h3@Wl)*dinv
//   GO : out += dinv * gather32(hwB32)
// Identity: gcn(h)[v] = dinv[v] * sum_{s in nbr(v) u {v}} (hW*dinv)[s] + b

#define HID 64
#define LAT 32
#define BSH 3          // 8 nodes per bucket
#define BCAP 256       // bucket capacity (mean 128, ~11 sigma margin)

static inline int cdiv(long long a, long long b) { return (int)((a + b - 1) / b); }

// ---------------- CSR build ----------------

__global__ void zero_kernel(int* __restrict__ p, int n) {
    int i = blockIdx.x * blockDim.x + threadIdx.x;
    if (i < n) p[i] = 0;
}

__global__ void bucket_fill_kernel(const int* __restrict__ src, const int* __restrict__ dst,
                                   int* __restrict__ bcur, unsigned* __restrict__ bbuf, int E) {
    int e = blockIdx.x * blockDim.x + threadIdx.x;
    if (e >= E) return;
    int s = src[e], d = dst[e];
    int b = d >> BSH;
    int pos = atomicAdd(&bcur[b], 1);
    if (pos < BCAP)
        bbuf[(size_t)b * BCAP + pos] = ((unsigned)(d & ((1 << BSH) - 1)) << 17) | (unsigned)s;
}

__global__ void bscan_kernel(const int* __restrict__ bcur, int* __restrict__ bstart, int nb) {
    __shared__ int s[1024];
    __shared__ int carry;
    int t = threadIdx.x;
    if (t == 0) carry = 0;
    __syncthreads();
    for (int base = 0; base < nb; base += 1024) {
        int i = base + t;
        int v = (i < nb) ? bcur[i] : 0;
        s[t] = v;
        __syncthreads();
        for (int off = 1; off < 1024; off <<= 1) {
            int x = (t >= off) ? s[t - off] : 0;
            __syncthreads();
            s[t] += x;
            __syncthreads();
        }
        if (i < nb) bstart[i] = carry + s[t] - v;
        __syncthreads();
        if (t == 1023) carry += s[1023];
        __syncthreads();
    }
}

__global__ void build_csr_kernel(const int* __restrict__ bcur, const int* __restrict__ bstart,
                                 const unsigned* __restrict__ bbuf, int* __restrict__ csr,
                                 int* __restrict__ rowstart, float* __restrict__ dinv,
                                 int n, int E) {
    __shared__ int lcount[1 << BSH], lpre[1 << BSH], lcur[1 << BSH];
    int b = blockIdx.x, t = threadIdx.x;
    int cnt = bcur[b];
    if (cnt > BCAP) cnt = BCAP;
    int bst = bstart[b];
    size_t ebase = (size_t)b * BCAP;

    if (t < (1 << BSH)) lcount[t] = 0;
    __syncthreads();

    unsigned rec[2];
    int nrec = 0;
    for (int i = t; i < cnt; i += 128) {
        unsigned p = bbuf[ebase + i];
        rec[nrec++] = p;
        atomicAdd(&lcount[p >> 17], 1);
    }
    __syncthreads();

    if (t == 0) {
        int run = 0;
        for (int k = 0; k < (1 << BSH); ++k) {
            lpre[k] = run;
            lcur[k] = run;
            run += lcount[k];
        }
    }
    __syncthreads();

    if (t < (1 << BSH)) {
        int v = (b << BSH) + t;
        if (v < n) {
            rowstart[v] = bst + lpre[t];
            dinv[v] = rsqrtf((float)(lcount[t] + 1));
        }
    }
    if (b == 0 && t == 0) rowstart[n] = E;

    for (int j = 0; j < nrec; ++j) {
        unsigned p = rec[j];
        int pos = bst + atomicAdd(&lcur[p >> 17], 1);
        csr[pos] = (int)(p & 0x1FFFFu);
    }
}

// ---------------- output init ----------------

__global__ void out_init_kernel(const float* __restrict__ bl, const float* __restrict__ bs,
                                float* __restrict__ out, int n) {
    long long t = (long long)blockIdx.x * blockDim.x + threadIdx.x;
    if (t >= (long long)n * LAT) return;
    int c = (int)(t & (LAT - 1));
    out[t] = bl[c] + bs[c] + bs[LAT + c] + bs[2 * LAT + c];
}

// ---------------- K0: input layer, fused, 4x4 register-tiled ----------------
// 64 rows/block. Phase1: h0 = x@Win + bin (rg 16x4rows, lc 16x4cols).
// Phase2a: hw = (h0@Wg0)*dinv. Phase2b: out += h0@Ws0 (sg 32x2rows, sc 8x4cols).

__global__ void input_fused_kernel(const float* __restrict__ x, const float* __restrict__ Win,
                                   const float* __restrict__ bin, const float* __restrict__ Wg0,
                                   const float* __restrict__ Ws0, const float* __restrict__ dinv,
                                   float* __restrict__ hw, float* __restrict__ out, int n) {
    __shared__ float xr[64 * 129];  // stride 129: bank = (row + k) % 32, conflict-free
    __shared__ float h0[64 * 68];   // stride 68: 2-way alias (free), 16B-aligned rows
    int t = threadIdx.x;
    int vbase = blockIdx.x * 64;

    for (int i = t; i < 64 * 128; i += 256) {
        int rr = i >> 7, kk = i & 127;
        long long g = (long long)(vbase + rr) * 128 + kk;
        xr[rr * 129 + kk] = (vbase + rr < n) ? x[g] : 0.f;
    }
    __syncthreads();

    int rg = t >> 4;        // 16 groups x 4 rows
    int lc = t & 15;        // 16 col-groups x 4 cols
    {
        float4 b4 = *(const float4*)&bin[4 * lc];
        float4 a0 = b4, a1 = b4, a2 = b4, a3 = b4;
#pragma unroll 8
        for (int k = 0; k < 128; ++k) {
            float4 w = *(const float4*)&Win[k * 64 + 4 * lc];
            float x0 = xr[(rg * 4 + 0) * 129 + k];
            float x1 = xr[(rg * 4 + 1) * 129 + k];
            float x2 = xr[(rg * 4 + 2) * 129 + k];
            float x3 = xr[(rg * 4 + 3) * 129 + k];
            a0.x = fmaf(x0, w.x, a0.x); a0.y = fmaf(x0, w.y, a0.y);
            a0.z = fmaf(x0, w.z, a0.z); a0.w = fmaf(x0, w.w, a0.w);
            a1.x = fmaf(x1, w.x, a1.x); a1.y = fmaf(x1, w.y, a1.y);
            a1.z = fmaf(x1, w.z, a1.z); a1.w = fmaf(x1, w.w, a1.w);
            a2.x = fmaf(x2, w.x, a2.x); a2.y = fmaf(x2, w.y, a2.y);
            a2.z = fmaf(x2, w.z, a2.z); a2.w = fmaf(x2, w.w, a2.w);
            a3.x = fmaf(x3, w.x, a3.x); a3.y = fmaf(x3, w.y, a3.y);
            a3.z = fmaf(x3, w.z, a3.z); a3.w = fmaf(x3, w.w, a3.w);
        }
        *(float4*)&h0[(rg * 4 + 0) * 68 + 4 * lc] = a0;
        *(float4*)&h0[(rg * 4 + 1) * 68 + 4 * lc] = a1;
        *(float4*)&h0[(rg * 4 + 2) * 68 + 4 * lc] = a2;
        *(float4*)&h0[(rg * 4 + 3) * 68 + 4 * lc] = a3;
    }
    __syncthreads();

    // Phase2a: hw = (h0 @ Wg0) * dinv
    {
        float4 a0, a1, a2, a3;
        a0 = a1 = a2 = a3 = make_float4(0.f, 0.f, 0.f, 0.f);
#pragma unroll 8
        for (int k = 0; k < 64; ++k) {
            float4 w = *(const float4*)&Wg0[k * 64 + 4 * lc];
            float x0 = h0[(rg * 4 + 0) * 68 + k];
            float x1 = h0[(rg * 4 + 1) * 68 + k];
            float x2 = h0[(rg * 4 + 2) * 68 + k];
            float x3 = h0[(rg * 4 + 3) * 68 + k];
            a0.x = fmaf(x0, w.x, a0.x); a0.y = fmaf(x0, w.y, a0.y);
            a0.z = fmaf(x0, w.z, a0.z); a0.w = fmaf(x0, w.w, a0.w);
            a1.x = fmaf(x1, w.x, a1.x); a1.y = fmaf(x1, w.y, a1.y);
            a1.z = fmaf(x1, w.z, a1.z); a1.w = fmaf(x1, w.w, a1.w);
            a2.x = fmaf(x2, w.x, a2.x); a2.y = fmaf(x2, w.y, a2.y);
            a2.z = fmaf(x2, w.z, a2.z); a2.w = fmaf(x2, w.w, a2.w);
            a3.x = fmaf(x3, w.x, a3.x); a3.y = fmaf(x3, w.y, a3.y);
            a3.z = fmaf(x3, w.z, a3.z); a3.w = fmaf(x3, w.w, a3.w);
        }
#pragma unroll
        for (int r = 0; r < 4; ++r) {
            int v = vbase + rg * 4 + r;
            if (v < n) {
                float di = dinv[v];
                float4 a = (r == 0) ? a0 : (r == 1) ? a1 : (r == 2) ? a2 : a3;
                a.x *= di; a.y *= di; a.z *= di; a.w *= di;
                *(float4*)&hw[(size_t)v * 64 + 4 * lc] = a;
            }
        }
    }

    // Phase2b: out += h0 @ Ws0   (32 cols: sg 32x2rows, sc 8x4cols)
    {
        int sg = t >> 3, sc = t & 7;
        float4 a0, a1;
        a0 = a1 = make_float4(0.f, 0.f, 0.f, 0.f);
#pragma unroll 8
        for (int k = 0; k < 64; ++k) {
            float4 w = *(const float4*)&Ws0[k * 32 + 4 * sc];
            float x0 = h0[(sg * 2 + 0) * 68 + k];
            float x1 = h0[(sg * 2 + 1) * 68 + k];
            a0.x = fmaf(x0, w.x, a0.x); a0.y = fmaf(x0, w.y, a0.y);
            a0.z = fmaf(x0, w.z, a0.z); a0.w = fmaf(x0, w.w, a0.w);
            a1.x = fmaf(x1, w.x, a1.x); a1.y = fmaf(x1, w.y, a1.y);
            a1.z = fmaf(x1, w.z, a1.z); a1.w = fmaf(x1, w.w, a1.w);
        }
#pragma unroll
        for (int r = 0; r < 2; ++r) {
            int v = vbase + sg * 2 + r;
            if (v < n) {
                float4 a = (r == 0) ? a0 : a1;
                float4* op = (float4*)(out + (size_t)v * 32 + 4 * sc);
                float4 o = *op;
                o.x += a.x; o.y += a.y; o.z += a.z; o.w += a.w;
                *op = o;
            }
        }
    }
}

// ---------------- fused gather + transform, 64 nodes/block ----------------
// Phase1 (x4 batches of 16 nodes, 16 lanes each): gather + lrelu -> hL.
// Phase2a (!LAST): hwout = (hL@Wg)*dinv; Phase2b: out += hL@Ws.
// Phase2 (LAST): hwout32 = (hL@Ws)*dinv (Ws carries Wl).

template <bool LAST>
__global__ void gather_transform_kernel(const int* __restrict__ rowstart, const int* __restrict__ csr,
                                        const float* __restrict__ dinv, const float* __restrict__ hwin,
                                        const float* __restrict__ bias, const float* __restrict__ Wg,
                                        const float* __restrict__ Ws, float* __restrict__ hwout,
                                        float* __restrict__ out, int n) {
    __shared__ float hL[64 * 68];
    int t = threadIdx.x;
    int vbase = blockIdx.x * 64;
    int ns = t >> 4, lc = t & 15;

    float4 b4 = *(const float4*)&bias[4 * lc];
#pragma unroll
    for (int b = 0; b < 4; ++b) {
        int row = b * 16 + ns;
        int v = vbase + row;
        if (v < n) {
            int beg = rowstart[v];
            int end = rowstart[v + 1];
            float di = dinv[v];
            float4 acc = *(const float4*)&hwin[(size_t)v * 64 + 4 * lc];  // self (pre-scaled)
            const float* base = hwin + 4 * lc;
            int e = beg;
            for (; e + 3 < end; e += 4) {
                int s0 = csr[e], s1 = csr[e + 1], s2 = csr[e + 2], s3 = csr[e + 3];
                float4 g0 = *(const float4*)&base[(size_t)s0 * 64];
                float4 g1 = *(const float4*)&base[(size_t)s1 * 64];
                float4 g2 = *(const float4*)&base[(size_t)s2 * 64];
                float4 g3 = *(const float4*)&base[(size_t)s3 * 64];
                acc.x += (g0.x + g1.x) + (g2.x + g3.x);
                acc.y += (g0.y + g1.y) + (g2.y + g3.y);
                acc.z += (g0.z + g1.z) + (g2.z + g3.z);
                acc.w += (g0.w + g1.w) + (g2.w + g3.w);
            }
            for (; e < end; ++e) {
                float4 g0 = *(const float4*)&base[(size_t)csr[e] * 64];
                acc.x += g0.x; acc.y += g0.y; acc.z += g0.z; acc.w += g0.w;
            }
            float4 h;
            h.x = di * acc.x + b4.x; h.x = h.x > 0.f ? h.x : 0.2f * h.x;
            h.y = di * acc.y + b4.y; h.y = h.y > 0.f ? h.y : 0.2f * h.y;
            h.z = di * acc.z + b4.z; h.z = h.z > 0.f ? h.z : 0.2f * h.z;
            h.w = di * acc.w + b4.w; h.w = h.w > 0.f ? h.w : 0.2f * h.w;
            *(float4*)&hL[row * 68 + 4 * lc] = h;
        }
    }
    __syncthreads();

    if (!LAST) {
        // Phase2a: hwout = (hL @ Wg) * dinv
        int rg = t >> 4;
        float4 a0, a1, a2, a3;
        a0 = a1 = a2 = a3 = make_float4(0.f, 0.f, 0.f, 0.f);
#pragma unroll 8
        for (int k = 0; k < 64; ++k) {
            float4 w = *(const float4*)&Wg[k * 64 + 4 * lc];
            float x0 = hL[(rg * 4 + 0) * 68 + k];
            float x1 = hL[(rg * 4 + 1) * 68 + k];
            float x2 = hL[(rg * 4 + 2) * 68 + k];
            float x3 = hL[(rg * 4 + 3) * 68 + k];
            a0.x = fmaf(x0, w.x, a0.x); a0.y = fmaf(x0, w.y, a0.y);
            a0.z = fmaf(x0, w.z, a0.z); a0.w = fmaf(x0, w.w, a0.w);
            a1.x = fmaf(x1, w.x, a1.x); a1.y = fmaf(x1, w.y, a1.y);
            a1.z = fmaf(x1, w.z, a1.z); a1.w = fmaf(x1, w.w, a1.w);
            a2.x = fmaf(x2, w.x, a2.x); a2.y = fmaf(x2, w.y, a2.y);
            a2.z = fmaf(x2, w.z, a2.z); a2.w = fmaf(x2, w.w, a2.w);
            a3.x = fmaf(x3, w.x, a3.x); a3.y = fmaf(x3, w.y, a3.y);
            a3.z = fmaf(x3, w.z, a3.z); a3.w = fmaf(x3, w.w, a3.w);
        }
#pragma unroll
        for (int r = 0; r < 4; ++r) {
            int v = vbase + rg * 4 + r;
            if (v < n) {
                float di = dinv[v];
                float4 a = (r == 0) ? a0 : (r == 1) ? a1 : (r == 2) ? a2 : a3;
                a.x *= di; a.y *= di; a.z *= di; a.w *= di;
                *(float4*)&hwout[(size_t)v * 64 + 4 * lc] = a;
            }
        }

        // Phase2b: out += hL @ Ws
        int sg = t >> 3, sc = t & 7;
        float4 s0, s1;
        s0 = s1 = make_float4(0.f, 0.f, 0.f, 0.f);
#pragma unroll 8
        for (int k = 0; k < 64; ++k) {
            float4 w = *(const float4*)&Ws[k * 32 + 4 * sc];
            float x0 = hL[(sg * 2 + 0) * 68 + k];
            float x1 = hL[(sg * 2 + 1) * 68 + k];
            s0.x = fmaf(x0, w.x, s0.x); s0.y = fmaf(x0, w.y, s0.y);
            s0.z = fmaf(x0, w.z, s0.z); s0.w = fmaf(x0, w.w, s0.w);
            s1.x = fmaf(x1, w.x, s1.x); s1.y = fmaf(x1, w.y, s1.y);
            s1.z = fmaf(x1, w.z, s1.z); s1.w = fmaf(x1, w.w, s1.w);
        }
#pragma unroll
        for (int r = 0; r < 2; ++r) {
            int v = vbase + sg * 2 + r;
            if (v < n) {
                float4 a = (r == 0) ? s0 : s1;
                float4* op = (float4*)(out + (size_t)v * 32 + 4 * sc);
                float4 o = *op;
                o.x += a.x; o.y += a.y; o.z += a.z; o.w += a.w;
                *op = o;
            }
        }
    } else {
        // LAST: hwout32 = (hL @ Wl) * dinv
        int sg = t >> 3, sc = t & 7;
        float4 s0, s1;
        s0 = s1 = make_float4(0.f, 0.f, 0.f, 0.f);
#pragma unroll 8
        for (int k = 0; k < 64; ++k) {
            float4 w = *(const float4*)&Ws[k * 32 + 4 * sc];
            float x0 = hL[(sg * 2 + 0) * 68 + k];
            float x1 = hL[(sg * 2 + 1) * 68 + k];
            s0.x = fmaf(x0, w.x, s0.x); s0.y = fmaf(x0, w.y, s0.y);
            s0.z = fmaf(x0, w.z, s0.z); s0.w = fmaf(x0, w.w, s0.w);
            s1.x = fmaf(x1, w.x, s1.x); s1.y = fmaf(x1, w.y, s1.y);
            s1.z = fmaf(x1, w.z, s1.z); s1.w = fmaf(x1, w.w, s1.w);
        }
#pragma unroll
        for (int r = 0; r < 2; ++r) {
            int v = vbase + sg * 2 + r;
            if (v < n) {
                float di = dinv[v];
                float4 a = (r == 0) ? s0 : s1;
                a.x *= di; a.y *= di; a.z *= di; a.w *= di;
                *(float4*)&hwout[(size_t)v * 32 + 4 * sc] = a;
            }
        }
    }
}

// ---------------- final gather into output (32 ch, 8 lanes/node) ----------------

__global__ void gather_out_kernel(const int* __restrict__ rowstart, const int* __restrict__ csr,
                                  const float* __restrict__ dinv, const float* __restrict__ hwl,
                                  float* __restrict__ out, int n) {
    int t = threadIdx.x;
    int lr = t >> 3, lc = t & 7;
    int v = blockIdx.x * 32 + lr;
    if (v >= n) return;
    int beg = rowstart[v], end = rowstart[v + 1];
    float4 acc = *(const float4*)&hwl[(size_t)v * 32 + 4 * lc];
    const float* base = hwl + 4 * lc;
    int e = beg;
    for (; e + 3 < end; e += 4) {
        int s0 = csr[e], s1 = csr[e + 1], s2 = csr[e + 2], s3 = csr[e + 3];
        float4 a0 = *(const float4*)&base[(size_t)s0 * 32];
        float4 a1 = *(const float4*)&base[(size_t)s1 * 32];
        float4 a2 = *(const float4*)&base[(size_t)s2 * 32];
        float4 a3 = *(const float4*)&base[(size_t)s3 * 32];
        acc.x += (a0.x + a1.x) + (a2.x + a3.x);
        acc.y += (a0.y + a1.y) + (a2.y + a3.y);
        acc.z += (a0.z + a1.z) + (a2.z + a3.z);
        acc.w += (a0.w + a1.w) + (a2.w + a3.w);
    }
    for (; e < end; ++e) {
        float4 a0 = *(const float4*)&base[(size_t)csr[e] * 32];
        acc.x += a0.x; acc.y += a0.y; acc.z += a0.z; acc.w += a0.w;
    }
    float di = dinv[v];
    float4* op = (float4*)(out + (size_t)v * 32 + 4 * lc);
    float4 o = *op;
    o.x += di * acc.x; o.y += di * acc.y; o.z += di * acc.z; o.w += di * acc.w;
    *op = o;
}

// ---------------- launch ----------------

extern "C" void kernel_launch(void* const* d_in, const int* in_sizes, int n_in,
                              void* d_out, int out_size, void* d_ws, size_t ws_size,
                              hipStream_t stream) {
    const float* x    = (const float*)d_in[0];
    const int*   ei   = (const int*)d_in[1];
    const float* W_in = (const float*)d_in[2];
    const float* b_in = (const float*)d_in[3];
    const float* Wg   = (const float*)d_in[4];  // [3][64][64]
    const float* bg   = (const float*)d_in[5];  // [3][64]
    const float* Ws   = (const float*)d_in[6];  // [3][64][32]
    const float* bs   = (const float*)d_in[7];  // [3][32]
    const float* Wl   = (const float*)d_in[8];  // [64][32]
    const float* bl   = (const float*)d_in[9];  // [32]

    const int N = in_sizes[0] / 128;
    const int E = in_sizes[1] / 2;
    const int NB = cdiv(N, 1 << BSH);
    const int* srcp = ei;
    const int* dstp = ei + E;

    char* p = (char*)d_ws;
    float*    hwA      = (float*)p;    p += (size_t)N * HID * 4;
    float*    hwB      = (float*)p;    p += (size_t)N * HID * 4;
    unsigned* bbuf     = (unsigned*)p; p += (size_t)NB * BCAP * 4;
    int*      csr      = (int*)p;      p += (size_t)E * 4;
    int*      rowstart = (int*)p;      p += ((size_t)N + 1) * 4;
    float*    dinv     = (float*)p;    p += (size_t)N * 4;
    int*      bcur     = (int*)p;      p += (size_t)NB * 4;
    int*      bstart   = (int*)p;      p += (size_t)NB * 4;
    float*    out      = (float*)d_out;

    const int B = 256;

    zero_kernel<<<cdiv(NB, B), B, 0, stream>>>(bcur, NB);
    bucket_fill_kernel<<<cdiv(E, B), B, 0, stream>>>(srcp, dstp, bcur, bbuf, E);
    bscan_kernel<<<1, 1024, 0, stream>>>(bcur, bstart, NB);
    build_csr_kernel<<<NB, 128, 0, stream>>>(bcur, bstart, bbuf, csr, rowstart, dinv, N, E);

    out_init_kernel<<<cdiv((long long)N * LAT, B), B, 0, stream>>>(bl, bs, out, N);

    input_fused_kernel<<<cdiv(N, 64), B, 0, stream>>>(
        x, W_in, b_in, Wg, Ws, dinv, hwA, out, N);

    gather_transform_kernel<false><<<cdiv(N, 64), B, 0, stream>>>(
        rowstart, csr, dinv, hwA, bg, Wg + 4096, Ws + 2048, hwB, out, N);

    gather_transform_kernel<false><<<cdiv(N, 64), B, 0, stream>>>(
        rowstart, csr, dinv, hwB, bg + 64, Wg + 8192, Ws + 4096, hwA, out, N);

    gather_transform_kernel<true><<<cdiv(N, 64), B, 0, stream>>>(
        rowstart, csr, dinv, hwA, bg + 128, nullptr, Wl, hwB, nullptr, N);

    gather_out_kernel<<<cdiv(N, 32), B, 0, stream>>>(rowstart, csr, dinv, hwB, out, N);
}